// Round 2
// baseline (384.245 us; speedup 1.0000x reference)
//
#include <hip/hip_runtime.h>

// MHA: B=4, S=2048, D=1024, H=16, Dh=64.  M = B*S = 8192.
// bf16 MFMA layouts (verified):
//   32x32x16  C/D: col=lane&31, row=(r&3)+8*(r>>2)+4*(lane>>5)
//             A[m=lane&31][k=(lane>>5)*8+j] ; B[k=(lane>>5)*8+j][n=lane&31]
// Flash v7: rotated software pipeline. QK(it+1) issues at END of iter it;
// exp/pack/PV(it) consume sacc produced BEFORE the last barrier -> no wait on
// MFMA latency; VALU (exp/pack) hides under PV/QK matrix-pipe time. K has
// 2-iter prefetch depth, V 1-iter; one barrier/iter. In-register P via
// v_permlane32_swap_b32 (T12), setprio around MFMA clusters (T5),
// launch_bounds(256,4) to force VGPR<=128 -> 4 blocks/CU resident.
// GEMM v2: mode 2 (V^T output) computes C^T via swapped operands so stores
// are lane-contiguous (was 2B stores at 4KB lane stride).

typedef short bf16x8 __attribute__((ext_vector_type(8)));
typedef short bf16x4 __attribute__((ext_vector_type(4)));
typedef float f32x4 __attribute__((ext_vector_type(4)));
typedef float f32x16 __attribute__((ext_vector_type(16)));
typedef unsigned int u32x4 __attribute__((ext_vector_type(4)));

__device__ __forceinline__ short f2bf(float x) {  // RNE
    union { float f; unsigned int u; } un; un.f = x;
    unsigned int u = un.u;
    return (short)(unsigned short)((u + 0x7fffu + ((u >> 16) & 1u)) >> 16);
}

__device__ __forceinline__ void gll16(const void* g, void* l) {
    __builtin_amdgcn_global_load_lds(
        (const __attribute__((address_space(1))) void*)g,
        (__attribute__((address_space(3))) void*)l, 16, 0, 0);
}

// v_permlane32_swap_b32 a, b :  tmp = a.hi32lanes; a.hi = b.lo; b.lo = tmp
__device__ __forceinline__ void plswap(unsigned& a, unsigned& b) {
    asm("v_permlane32_swap_b32 %0, %1" : "+v"(a), "+v"(b));
}

// ---- fused fp32 -> bf16 convert ----
struct CvtArgs { const float* s[4]; unsigned short* d[4]; int n4; };
__global__ __launch_bounds__(256) void cvt_bf16(CvtArgs ca) {
    const float* s = ca.s[blockIdx.y];
    unsigned short* d = ca.d[blockIdx.y];
    int i = blockIdx.x * blockDim.x + threadIdx.x;
    int stride = gridDim.x * blockDim.x;
    const float4* s4 = reinterpret_cast<const float4*>(s);
    bf16x4* d4 = reinterpret_cast<bf16x4*>(d);
    for (; i < ca.n4; i += stride) {
        float4 x = s4[i];
        bf16x4 y;
        y[0] = f2bf(x.x); y[1] = f2bf(x.y); y[2] = f2bf(x.z); y[3] = f2bf(x.w);
        d4[i] = y;
    }
}

// ---- GEMM core: OUT[m][n] = Arg0[m] . Arg1[n]  (both row-major [.][1024]) ----
// mode 0: fp32 [M][N] out (m=token, n=feature)
// mode 1: bf16 [b*16+h][s][d] out (m=token, n=feature)
// mode 2: bf16 [b*16+h][d][s] out, SWAPPED operands: m=feature, n=token ->
//         stores are contiguous in n (token) across lanes.
__device__ __forceinline__ void gemm_core(const unsigned short* __restrict__ A,
                                          const unsigned short* __restrict__ W,
                                          const float* __restrict__ bias,
                                          float scale, void* __restrict__ out,
                                          int mode) {
    __shared__ unsigned short As[128 * 64];  // 128 rows x 128B, source-swizzled
    __shared__ unsigned short Bs[128 * 64];
    const int tid = threadIdx.x;
    const int m0 = (mode == 2 ? blockIdx.x : blockIdx.y) * 128;
    const int n0 = (mode == 2 ? blockIdx.y : blockIdx.x) * 128;
    const int wave = tid >> 6, lane = tid & 63;
    const int wm = (wave >> 1) * 64, wn = (wave & 1) * 64;
    const int l15 = lane & 15, quad = lane >> 4;
    const int srow = tid >> 3;
    const int scol = ((tid & 7) ^ (srow & 7)) * 8;
    const int cb = (l15 & 7);

    f32x4 acc[4][4] = {};

    for (int k0 = 0; k0 < 1024; k0 += 64) {
        __syncthreads();
#pragma unroll
        for (int ro = 0; ro < 4; ++ro) {
            gll16(&A[(size_t)(m0 + ro * 32 + srow) * 1024 + k0 + scol], &As[ro * 2048 + tid * 8]);
            gll16(&W[(size_t)(n0 + ro * 32 + srow) * 1024 + k0 + scol], &Bs[ro * 2048 + tid * 8]);
        }
        __syncthreads();
#pragma unroll
        for (int kk = 0; kk < 2; ++kk) {
            const int co = ((4 * kk + quad) ^ cb) * 8;
            bf16x8 a[4], b[4];
#pragma unroll
            for (int i = 0; i < 4; ++i)
                a[i] = *reinterpret_cast<bf16x8*>(&As[(wm + i * 16 + l15) * 64 + co]);
#pragma unroll
            for (int j = 0; j < 4; ++j)
                b[j] = *reinterpret_cast<bf16x8*>(&Bs[(wn + j * 16 + l15) * 64 + co]);
#pragma unroll
            for (int i = 0; i < 4; ++i)
#pragma unroll
                for (int j = 0; j < 4; ++j)
                    acc[i][j] = __builtin_amdgcn_mfma_f32_16x16x32_bf16(a[i], b[j], acc[i][j], 0, 0, 0);
        }
    }

#pragma unroll
    for (int i = 0; i < 4; ++i) {
#pragma unroll
        for (int j = 0; j < 4; ++j) {
#pragma unroll
            for (int r = 0; r < 4; ++r) {
                int m = m0 + wm + i * 16 + quad * 4 + r;
                int n = n0 + wn + j * 16 + l15;
                float val = (acc[i][j][r] + bias[mode == 2 ? m : n]) * scale;
                if (mode == 0) {
                    reinterpret_cast<float*>(out)[(size_t)m * 1024 + n] = val;
                } else if (mode == 1) {
                    int b_ = m >> 11, s = m & 2047, h = n >> 6, d = n & 63;
                    size_t off = (size_t)((b_ * 16 + h) * 2048 + s) * 64 + d;
                    reinterpret_cast<unsigned short*>(out)[off] = (unsigned short)f2bf(val);
                } else {  // mode 2: m = feature (h,d), n = token (b,s)
                    int h = m >> 6, d = m & 63, b_ = n >> 11, s = n & 2047;
                    size_t off = (size_t)((b_ * 16 + h) * 64 + d) * 2048 + s;
                    reinterpret_cast<unsigned short*>(out)[off] = (unsigned short)f2bf(val);
                }
            }
        }
    }
}

struct QkvArgs {
    const unsigned short* A[3];
    const unsigned short* W[3];
    const float* bias[3];
    float scale[3];
    unsigned short* out[3];
    int mode[3];
};
__global__ __launch_bounds__(256) void gemm_qkv(QkvArgs ga) {
    int z = blockIdx.z;
    gemm_core(ga.A[z], ga.W[z], ga.bias[z], ga.scale[z], ga.out[z], ga.mode[z]);
}

__global__ __launch_bounds__(256) void gemm_wo(const unsigned short* __restrict__ A,
                                               const unsigned short* __restrict__ W,
                                               const float* __restrict__ bias,
                                               float* __restrict__ out) {
    gemm_core(A, W, bias, 1.0f, out, 0);
}

// ---- Flash v7: rotated pipeline, 32x32x16, in-register P ----
// Qh,Kh: [64][2048][64]; Vt: [64][64][2048]; Oa: [8192][1024] bf16.
// Q pre-scaled by 0.125*log2(e) -> exp2 directly. Block = (bh, 128 q), 4 waves.

// exp2(sacc[MT]) -> row-sum into lacc -> pack bf16 -> permlane -> 4 PV MFMAs
#define SOFTMAX_PV(MT, VBASE)                                                        \
    {                                                                                \
        float e[16];                                                                 \
        _Pragma("unroll")                                                            \
        for (int r = 0; r < 16; ++r) e[r] = __builtin_amdgcn_exp2f(sacc[MT][r]);     \
        lacc += ((e[0] + e[1]) + (e[2] + e[3])) + ((e[4] + e[5]) + (e[6] + e[7])) +  \
                ((e[8] + e[9]) + (e[10] + e[11])) + ((e[12] + e[13]) + (e[14] + e[15])); \
        unsigned w[8];                                                               \
        _Pragma("unroll")                                                            \
        for (int t = 0; t < 8; ++t) {                                                \
            union { float f; unsigned u; } a0{e[2 * t]}, a1{e[2 * t + 1]};           \
            w[t] = __builtin_amdgcn_perm(a1.u + 0x8000u, a0.u + 0x8000u, 0x07060302u); \
        }                                                                            \
        plswap(w[0], w[2]); plswap(w[1], w[3]);                                      \
        plswap(w[4], w[6]); plswap(w[5], w[7]);                                      \
        u32x4 t0; t0[0] = w[0]; t0[1] = w[1]; t0[2] = w[2]; t0[3] = w[3];            \
        u32x4 t1; t1[0] = w[4]; t1[1] = w[5]; t1[2] = w[6]; t1[3] = w[7];            \
        bf16x8 pa0 = __builtin_bit_cast(bf16x8, t0);                                 \
        bf16x8 pa1 = __builtin_bit_cast(bf16x8, t1);                                 \
        __builtin_amdgcn_s_setprio(1);                                               \
        _Pragma("unroll")                                                            \
        for (int nt = 0; nt < 2; ++nt) {                                             \
            bf16x8 bv0 = *reinterpret_cast<const bf16x8*>(&(VBASE)[rowoff[nt] + chx[2 * (MT)]]); \
            bf16x8 bv1 = *reinterpret_cast<const bf16x8*>(&(VBASE)[rowoff[nt] + chx[2 * (MT) + 1]]); \
            o[nt] = __builtin_amdgcn_mfma_f32_32x32x16_bf16(pa0, bv0, o[nt], 0, 0, 0); \
            o[nt] = __builtin_amdgcn_mfma_f32_32x32x16_bf16(pa1, bv1, o[nt], 0, 0, 0); \
        }                                                                            \
        __builtin_amdgcn_s_setprio(0);                                               \
    }

// sacc = K_tile . Q^T from KBASE (8 MFMAs, 8 ds_read_b128)
#define QK_TILE(KBASE)                                                               \
    {                                                                                \
        f32x16 zz = {};                                                              \
        sacc[0] = zz; sacc[1] = zz;                                                  \
        __builtin_amdgcn_s_setprio(1);                                               \
        _Pragma("unroll")                                                            \
        for (int c = 0; c < 4; ++c) {                                                \
            bf16x8 ak0 = *reinterpret_cast<const bf16x8*>(&(KBASE)[rowoff[0] + chx[c]]); \
            bf16x8 ak1 = *reinterpret_cast<const bf16x8*>(&(KBASE)[rowoff[1] + chx[c]]); \
            sacc[0] = __builtin_amdgcn_mfma_f32_32x32x16_bf16(ak0, qreg[c], sacc[0], 0, 0, 0); \
            sacc[1] = __builtin_amdgcn_mfma_f32_32x32x16_bf16(ak1, qreg[c], sacc[1], 0, 0, 0); \
        }                                                                            \
        __builtin_amdgcn_s_setprio(0);                                               \
    }

__global__ __launch_bounds__(256, 4) void flash_attn(const unsigned short* __restrict__ Qh,
                                                     const unsigned short* __restrict__ Kh,
                                                     const unsigned short* __restrict__ Vt,
                                                     unsigned short* __restrict__ Oa) {
    __shared__ unsigned short Ks[2][64 * 64];   // [kv][d], source-swizzled chunks
    __shared__ unsigned short Vs[2][64 * 64];   // V^T window [d][kv]
    const int tid = threadIdx.x;
    const int bh = blockIdx.y;
    const int q0 = blockIdx.x * 128;
    const unsigned short* Qb = Qh + (size_t)bh * 2048 * 64;
    const unsigned short* Kb = Kh + (size_t)bh * 2048 * 64;
    const unsigned short* Vb = Vt + (size_t)bh * 64 * 2048;
    const int wave = tid >> 6, lane = tid & 63;
    const int l31 = lane & 31, hi = lane >> 5;
    const int wq = wave * 32;
    const int srow = tid >> 3;                       // 0..31 per round
    const int scol = ((tid & 7) ^ (srow & 7)) * 8;   // swizzled source chunk

    // per-lane LDS read offsets (in shorts): row stride 64, chunk XOR row&7
    int chx[4], rowoff[2];
#pragma unroll
    for (int c = 0; c < 4; ++c) chx[c] = ((c * 2 + hi) ^ (l31 & 7)) * 8;
    rowoff[0] = l31 * 64;
    rowoff[1] = (32 + l31) * 64;

    // Q fragments (B-operand): qreg[c] = Q[q0+wq+l31][c*16 + hi*8 .. +8]
    bf16x8 qreg[4];
#pragma unroll
    for (int c = 0; c < 4; ++c)
        qreg[c] = *reinterpret_cast<const bf16x8*>(
            &Qb[(size_t)(q0 + wq + l31) * 64 + c * 16 + hi * 8]);

    f32x16 o[2] = {};
    f32x16 sacc[2];
    float lacc = 0.f;

    // prologue: stage K(0)->Ks[0], V(0)->Vs[0], K(1)->Ks[1]
#pragma unroll
    for (int ro = 0; ro < 2; ++ro) {
        gll16(&Kb[(size_t)(ro * 32 + srow) * 64 + scol], &Ks[0][ro * 2048 + tid * 8]);
        gll16(&Vb[(size_t)(ro * 32 + srow) * 2048 + scol], &Vs[0][ro * 2048 + tid * 8]);
        gll16(&Kb[(size_t)(64 + ro * 32 + srow) * 64 + scol], &Ks[1][ro * 2048 + tid * 8]);
    }
    __syncthreads();
    QK_TILE(Ks[0]);      // sacc = S(0)
    __syncthreads();     // all waves done with Ks[0] before iter-0 DMA overwrites it

    for (int it = 0; it < 31; ++it) {
        const int cur = it & 1, nxt = cur ^ 1;
        // prefetch: K(it+2) into the K buffer freed by last iter's QK
        if (it < 30) {
            const int kvn = (it + 2) * 64;
#pragma unroll
            for (int ro = 0; ro < 2; ++ro)
                gll16(&Kb[(size_t)(kvn + ro * 32 + srow) * 64 + scol], &Ks[cur][ro * 2048 + tid * 8]);
        }
        // prefetch: V(it+1) into the V buffer freed by last iter's PV
        {
            const int kvn = (it + 1) * 64;
#pragma unroll
            for (int ro = 0; ro < 2; ++ro)
                gll16(&Vb[(size_t)(ro * 32 + srow) * 2048 + kvn + scol], &Vs[nxt][ro * 2048 + tid * 8]);
        }

        // consume sacc(it) (produced before last barrier -> no MFMA-latency wait)
        SOFTMAX_PV(0, Vs[cur]);
        SOFTMAX_PV(1, Vs[cur]);

        // produce sacc(it+1) for next iteration
        QK_TILE(Ks[nxt]);

        __syncthreads();  // drains DMA (vmcnt) + orders buffer reuse
    }
    // tail: consume sacc(31); V(31) staged at it=30 into Vs[1]
    SOFTMAX_PV(0, Vs[1]);
    SOFTMAX_PV(1, Vs[1]);

    // epilogue: full l per q (cross-half add), redistribute 1/l to o's row layout
    float lfull = lacc + __shfl_xor(lacc, 32, 64);
    float rinv = 1.0f / lfull;  // valid for q = wq + l31 (both halves)
    const int b_ = bh >> 4, h = bh & 15;
#pragma unroll
    for (int r = 0; r < 16; ++r) {
        const int qrow = (r & 3) + 8 * (r >> 2) + 4 * hi;
        const float rl = __shfl(rinv, qrow, 64);
        const int s = q0 + wq + qrow;
#pragma unroll
        for (int nt = 0; nt < 2; ++nt) {
            const int d = nt * 32 + l31;
            Oa[(size_t)(b_ * 2048 + s) * 1024 + h * 64 + d] =
                (unsigned short)f2bf(o[nt][r] * rl);
        }
    }
}

extern "C" void kernel_launch(void* const* d_in, const int* in_sizes, int n_in,
                              void* d_out, int out_size, void* d_ws, size_t ws_size,
                              hipStream_t stream) {
    const float* q  = (const float*)d_in[0];
    const float* k  = (const float*)d_in[1];
    const float* v  = (const float*)d_in[2];
    const float* Wq = (const float*)d_in[3];
    const float* bq = (const float*)d_in[4];
    const float* Wk = (const float*)d_in[5];
    const float* bk = (const float*)d_in[6];
    const float* Wv = (const float*)d_in[7];
    const float* bv = (const float*)d_in[8];
    const float* Wo = (const float*)d_in[9];
    const float* bo = (const float*)d_in[10];

    const size_t E = (size_t)8192 * 1024;
    const size_t WE = (size_t)1024 * 1024;
    // aliasing (sequential dependency chain): r0=q_bf->Kh ; r1=k_bf->Vt ; r2=v_bf->Ao ; r3=Qh
    unsigned short* r0 = (unsigned short*)d_ws;
    unsigned short* r1 = r0 + E;
    unsigned short* r2 = r1 + E;
    unsigned short* r3 = r2 + E;
    unsigned short* wqb = r3 + E;
    unsigned short* wkb = wqb + WE;
    unsigned short* wvb = wkb + WE;
    unsigned short* wob = wvb + WE;

    CvtArgs ca;
    ca.s[0] = q; ca.d[0] = r0;
    ca.s[1] = k; ca.d[1] = r1;
    ca.s[2] = v; ca.d[2] = r2;
    ca.s[3] = q; ca.d[3] = r0;  // unused (grid.y = 3)
    ca.n4 = (int)(E / 4);
    cvt_bf16<<<dim3(1024, 3), 256, 0, stream>>>(ca);

    CvtArgs cw;
    cw.s[0] = Wq; cw.d[0] = wqb;
    cw.s[1] = Wk; cw.d[1] = wkb;
    cw.s[2] = Wv; cw.d[2] = wvb;
    cw.s[3] = Wo; cw.d[3] = wob;
    cw.n4 = (int)(WE / 4);
    cvt_bf16<<<dim3(256, 4), 256, 0, stream>>>(cw);

    const float QSCALE = 0.125f * 1.44269504088896340736f;  // fold log2(e) for exp2

    QkvArgs ga;
    ga.A[0] = r0;  ga.W[0] = wqb; ga.bias[0] = bq; ga.scale[0] = QSCALE; ga.out[0] = r3; ga.mode[0] = 1;
    ga.A[1] = r1;  ga.W[1] = wkb; ga.bias[1] = bk; ga.scale[1] = 1.0f;   ga.out[1] = r0; ga.mode[1] = 1;
    ga.A[2] = wvb; ga.W[2] = r2;  ga.bias[2] = bv; ga.scale[2] = 1.0f;   ga.out[2] = r1; ga.mode[2] = 2;  // swapped: C^T
    gemm_qkv<<<dim3(8, 64, 3), 256, 0, stream>>>(ga);

    flash_attn<<<dim3(16, 64), 256, 0, stream>>>(r3, r0, r1, r2);  // Ao = r2
    gemm_wo<<<dim3(8, 64), 256, 0, stream>>>(r2, wob, bo, (float*)d_out);
}

// Round 4
// 368.560 us; speedup vs baseline: 1.0426x; 1.0426x over previous
//
#include <hip/hip_runtime.h>

// MHA: B=4, S=2048, D=1024, H=16, Dh=64.  M = B*S = 8192.
// bf16 MFMA layouts (verified):
//   32x32x16  C/D: col=lane&31, row=(r&3)+8*(r>>2)+4*(lane>>5)
//             A[m=lane&31][k=(lane>>5)*8+j] ; B[k=(lane>>5)*8+j][n=lane&31]
// GEMM v3: T3-minimum rotated double-buffer. STAGE(t+1) issued BEFORE compute(t),
// ONE barrier/K-step; the barrier's implicit vmcnt(0) drains the prefetch after
// ~32 MFMAs have covered the DMA latency. Mode-2 operand swap REVERTED (measured
// regression in R2: qkv <107 -> 115 us).
// Flash v7 (unchanged): rotated pipeline, QK(it+1) at end of iter it; in-register
// P via v_permlane32_swap_b32; setprio on MFMA clusters; launch_bounds(256,4).
// R3 NOTE: identical resubmit — R3 bench failed on infra (container), no data.

typedef short bf16x8 __attribute__((ext_vector_type(8)));
typedef short bf16x4 __attribute__((ext_vector_type(4)));
typedef float f32x4 __attribute__((ext_vector_type(4)));
typedef float f32x16 __attribute__((ext_vector_type(16)));
typedef unsigned int u32x4 __attribute__((ext_vector_type(4)));

__device__ __forceinline__ short f2bf(float x) {  // RNE
    union { float f; unsigned int u; } un; un.f = x;
    unsigned int u = un.u;
    return (short)(unsigned short)((u + 0x7fffu + ((u >> 16) & 1u)) >> 16);
}

__device__ __forceinline__ void gll16(const void* g, void* l) {
    __builtin_amdgcn_global_load_lds(
        (const __attribute__((address_space(1))) void*)g,
        (__attribute__((address_space(3))) void*)l, 16, 0, 0);
}

// v_permlane32_swap_b32 a, b :  tmp = a.hi32lanes; a.hi = b.lo; b.lo = tmp
__device__ __forceinline__ void plswap(unsigned& a, unsigned& b) {
    asm("v_permlane32_swap_b32 %0, %1" : "+v"(a), "+v"(b));
}

// ---- fused fp32 -> bf16 convert ----
struct CvtArgs { const float* s[4]; unsigned short* d[4]; int n4; };
__global__ __launch_bounds__(256) void cvt_bf16(CvtArgs ca) {
    const float* s = ca.s[blockIdx.y];
    unsigned short* d = ca.d[blockIdx.y];
    int i = blockIdx.x * blockDim.x + threadIdx.x;
    int stride = gridDim.x * blockDim.x;
    const float4* s4 = reinterpret_cast<const float4*>(s);
    bf16x4* d4 = reinterpret_cast<bf16x4*>(d);
    for (; i < ca.n4; i += stride) {
        float4 x = s4[i];
        bf16x4 y;
        y[0] = f2bf(x.x); y[1] = f2bf(x.y); y[2] = f2bf(x.z); y[3] = f2bf(x.w);
        d4[i] = y;
    }
}

// ---- GEMM core: C[8192][1024] = A @ W^T, val = (acc+bias)*scale ----
// mode 0: fp32 [M][N] ; mode 1: bf16 [b*16+h][s][d] ; mode 2: bf16 [b*16+h][d][s]
// Rotated double-buffer: stage K-tile t+1 while computing t; one barrier/iter.
__device__ __forceinline__ void gemm_core(const unsigned short* __restrict__ A,
                                          const unsigned short* __restrict__ W,
                                          const float* __restrict__ bias,
                                          float scale, void* __restrict__ out,
                                          int mode) {
    __shared__ unsigned short As[2][128 * 64];  // 128 rows x 128B, source-swizzled
    __shared__ unsigned short Bs[2][128 * 64];
    const int tid = threadIdx.x;
    const int m0 = blockIdx.y * 128, n0 = blockIdx.x * 128;
    const int wave = tid >> 6, lane = tid & 63;
    const int wm = (wave >> 1) * 64, wn = (wave & 1) * 64;
    const int l15 = lane & 15, quad = lane >> 4;
    const int srow = tid >> 3;
    const int scol = ((tid & 7) ^ (srow & 7)) * 8;
    const int cb = (l15 & 7);

    f32x4 acc[4][4] = {};

    // prologue: stage K-tile 0 into buf 0
#pragma unroll
    for (int ro = 0; ro < 4; ++ro) {
        gll16(&A[(size_t)(m0 + ro * 32 + srow) * 1024 + scol], &As[0][ro * 2048 + tid * 8]);
        gll16(&W[(size_t)(n0 + ro * 32 + srow) * 1024 + scol], &Bs[0][ro * 2048 + tid * 8]);
    }
    __syncthreads();  // vmcnt(0) drain + barrier

    for (int kt = 0; kt < 16; ++kt) {
        const int cur = kt & 1;
        if (kt < 15) {  // issue next-tile DMA into the other buffer (no wait)
            const int k0 = (kt + 1) * 64;
#pragma unroll
            for (int ro = 0; ro < 4; ++ro) {
                gll16(&A[(size_t)(m0 + ro * 32 + srow) * 1024 + k0 + scol], &As[cur ^ 1][ro * 2048 + tid * 8]);
                gll16(&W[(size_t)(n0 + ro * 32 + srow) * 1024 + k0 + scol], &Bs[cur ^ 1][ro * 2048 + tid * 8]);
            }
        }
#pragma unroll
        for (int kk = 0; kk < 2; ++kk) {
            const int co = ((4 * kk + quad) ^ cb) * 8;
            bf16x8 a[4], b[4];
#pragma unroll
            for (int i = 0; i < 4; ++i)
                a[i] = *reinterpret_cast<bf16x8*>(&As[cur][(wm + i * 16 + l15) * 64 + co]);
#pragma unroll
            for (int j = 0; j < 4; ++j)
                b[j] = *reinterpret_cast<bf16x8*>(&Bs[cur][(wn + j * 16 + l15) * 64 + co]);
#pragma unroll
            for (int i = 0; i < 4; ++i)
#pragma unroll
                for (int j = 0; j < 4; ++j)
                    acc[i][j] = __builtin_amdgcn_mfma_f32_16x16x32_bf16(a[i], b[j], acc[i][j], 0, 0, 0);
        }
        __syncthreads();  // waves done reading buf[cur]; next-tile DMA landed
    }

#pragma unroll
    for (int i = 0; i < 4; ++i) {
#pragma unroll
        for (int j = 0; j < 4; ++j) {
#pragma unroll
            for (int r = 0; r < 4; ++r) {
                int m = m0 + wm + i * 16 + quad * 4 + r;
                int n = n0 + wn + j * 16 + l15;
                float val = (acc[i][j][r] + bias[n]) * scale;
                if (mode == 0) {
                    reinterpret_cast<float*>(out)[(size_t)m * 1024 + n] = val;
                } else {
                    int b_ = m >> 11, s = m & 2047, h = n >> 6, d = n & 63;
                    size_t off = (mode == 1)
                                     ? ((size_t)((b_ * 16 + h) * 2048 + s) * 64 + d)
                                     : ((size_t)((b_ * 16 + h) * 64 + d) * 2048 + s);
                    reinterpret_cast<unsigned short*>(out)[off] = (unsigned short)f2bf(val);
                }
            }
        }
    }
}

struct QkvArgs {
    const unsigned short* A[3];
    const unsigned short* W[3];
    const float* bias[3];
    float scale[3];
    unsigned short* out[3];
    int mode[3];
};
__global__ __launch_bounds__(256) void gemm_qkv(QkvArgs ga) {
    int z = blockIdx.z;
    gemm_core(ga.A[z], ga.W[z], ga.bias[z], ga.scale[z], ga.out[z], ga.mode[z]);
}

__global__ __launch_bounds__(256) void gemm_wo(const unsigned short* __restrict__ A,
                                               const unsigned short* __restrict__ W,
                                               const float* __restrict__ bias,
                                               float* __restrict__ out) {
    gemm_core(A, W, bias, 1.0f, out, 0);
}

// ---- Flash v7: rotated pipeline, 32x32x16, in-register P ----
// Qh,Kh: [64][2048][64]; Vt: [64][64][2048]; Oa: [8192][1024] bf16.
// Q pre-scaled by 0.125*log2(e) -> exp2 directly. Block = (bh, 128 q), 4 waves.

// exp2(sacc[MT]) -> row-sum into lacc -> pack bf16 -> permlane -> 4 PV MFMAs
#define SOFTMAX_PV(MT, VBASE)                                                        \
    {                                                                                \
        float e[16];                                                                 \
        _Pragma("unroll")                                                            \
        for (int r = 0; r < 16; ++r) e[r] = __builtin_amdgcn_exp2f(sacc[MT][r]);     \
        lacc += ((e[0] + e[1]) + (e[2] + e[3])) + ((e[4] + e[5]) + (e[6] + e[7])) +  \
                ((e[8] + e[9]) + (e[10] + e[11])) + ((e[12] + e[13]) + (e[14] + e[15])); \
        unsigned w[8];                                                               \
        _Pragma("unroll")                                                            \
        for (int t = 0; t < 8; ++t) {                                                \
            union { float f; unsigned u; } a0{e[2 * t]}, a1{e[2 * t + 1]};           \
            w[t] = __builtin_amdgcn_perm(a1.u + 0x8000u, a0.u + 0x8000u, 0x07060302u); \
        }                                                                            \
        plswap(w[0], w[2]); plswap(w[1], w[3]);                                      \
        plswap(w[4], w[6]); plswap(w[5], w[7]);                                      \
        u32x4 t0; t0[0] = w[0]; t0[1] = w[1]; t0[2] = w[2]; t0[3] = w[3];            \
        u32x4 t1; t1[0] = w[4]; t1[1] = w[5]; t1[2] = w[6]; t1[3] = w[7];            \
        bf16x8 pa0 = __builtin_bit_cast(bf16x8, t0);                                 \
        bf16x8 pa1 = __builtin_bit_cast(bf16x8, t1);                                 \
        __builtin_amdgcn_s_setprio(1);                                               \
        _Pragma("unroll")                                                            \
        for (int nt = 0; nt < 2; ++nt) {                                             \
            bf16x8 bv0 = *reinterpret_cast<const bf16x8*>(&(VBASE)[rowoff[nt] + chx[2 * (MT)]]); \
            bf16x8 bv1 = *reinterpret_cast<const bf16x8*>(&(VBASE)[rowoff[nt] + chx[2 * (MT) + 1]]); \
            o[nt] = __builtin_amdgcn_mfma_f32_32x32x16_bf16(pa0, bv0, o[nt], 0, 0, 0); \
            o[nt] = __builtin_amdgcn_mfma_f32_32x32x16_bf16(pa1, bv1, o[nt], 0, 0, 0); \
        }                                                                            \
        __builtin_amdgcn_s_setprio(0);                                               \
    }

// sacc = K_tile . Q^T from KBASE (8 MFMAs, 8 ds_read_b128)
#define QK_TILE(KBASE)                                                               \
    {                                                                                \
        f32x16 zz = {};                                                              \
        sacc[0] = zz; sacc[1] = zz;                                                  \
        __builtin_amdgcn_s_setprio(1);                                               \
        _Pragma("unroll")                                                            \
        for (int c = 0; c < 4; ++c) {                                                \
            bf16x8 ak0 = *reinterpret_cast<const bf16x8*>(&(KBASE)[rowoff[0] + chx[c]]); \
            bf16x8 ak1 = *reinterpret_cast<const bf16x8*>(&(KBASE)[rowoff[1] + chx[c]]); \
            sacc[0] = __builtin_amdgcn_mfma_f32_32x32x16_bf16(ak0, qreg[c], sacc[0], 0, 0, 0); \
            sacc[1] = __builtin_amdgcn_mfma_f32_32x32x16_bf16(ak1, qreg[c], sacc[1], 0, 0, 0); \
        }                                                                            \
        __builtin_amdgcn_s_setprio(0);                                               \
    }

__global__ __launch_bounds__(256, 4) void flash_attn(const unsigned short* __restrict__ Qh,
                                                     const unsigned short* __restrict__ Kh,
                                                     const unsigned short* __restrict__ Vt,
                                                     unsigned short* __restrict__ Oa) {
    __shared__ unsigned short Ks[2][64 * 64];   // [kv][d], source-swizzled chunks
    __shared__ unsigned short Vs[2][64 * 64];   // V^T window [d][kv]
    const int tid = threadIdx.x;
    const int bh = blockIdx.y;
    const int q0 = blockIdx.x * 128;
    const unsigned short* Qb = Qh + (size_t)bh * 2048 * 64;
    const unsigned short* Kb = Kh + (size_t)bh * 2048 * 64;
    const unsigned short* Vb = Vt + (size_t)bh * 64 * 2048;
    const int wave = tid >> 6, lane = tid & 63;
    const int l31 = lane & 31, hi = lane >> 5;
    const int wq = wave * 32;
    const int srow = tid >> 3;                       // 0..31 per round
    const int scol = ((tid & 7) ^ (srow & 7)) * 8;   // swizzled source chunk

    // per-lane LDS read offsets (in shorts): row stride 64, chunk XOR row&7
    int chx[4], rowoff[2];
#pragma unroll
    for (int c = 0; c < 4; ++c) chx[c] = ((c * 2 + hi) ^ (l31 & 7)) * 8;
    rowoff[0] = l31 * 64;
    rowoff[1] = (32 + l31) * 64;

    // Q fragments (B-operand): qreg[c] = Q[q0+wq+l31][c*16 + hi*8 .. +8]
    bf16x8 qreg[4];
#pragma unroll
    for (int c = 0; c < 4; ++c)
        qreg[c] = *reinterpret_cast<const bf16x8*>(
            &Qb[(size_t)(q0 + wq + l31) * 64 + c * 16 + hi * 8]);

    f32x16 o[2] = {};
    f32x16 sacc[2];
    float lacc = 0.f;

    // prologue: stage K(0)->Ks[0], V(0)->Vs[0], K(1)->Ks[1]
#pragma unroll
    for (int ro = 0; ro < 2; ++ro) {
        gll16(&Kb[(size_t)(ro * 32 + srow) * 64 + scol], &Ks[0][ro * 2048 + tid * 8]);
        gll16(&Vb[(size_t)(ro * 32 + srow) * 2048 + scol], &Vs[0][ro * 2048 + tid * 8]);
        gll16(&Kb[(size_t)(64 + ro * 32 + srow) * 64 + scol], &Ks[1][ro * 2048 + tid * 8]);
    }
    __syncthreads();
    QK_TILE(Ks[0]);      // sacc = S(0)
    __syncthreads();     // all waves done with Ks[0] before iter-0 DMA overwrites it

    for (int it = 0; it < 31; ++it) {
        const int cur = it & 1, nxt = cur ^ 1;
        // prefetch: K(it+2) into the K buffer freed by last iter's QK
        if (it < 30) {
            const int kvn = (it + 2) * 64;
#pragma unroll
            for (int ro = 0; ro < 2; ++ro)
                gll16(&Kb[(size_t)(kvn + ro * 32 + srow) * 64 + scol], &Ks[cur][ro * 2048 + tid * 8]);
        }
        // prefetch: V(it+1) into the V buffer freed by last iter's PV
        {
            const int kvn = (it + 1) * 64;
#pragma unroll
            for (int ro = 0; ro < 2; ++ro)
                gll16(&Vb[(size_t)(ro * 32 + srow) * 2048 + kvn + scol], &Vs[nxt][ro * 2048 + tid * 8]);
        }

        // consume sacc(it) (produced before last barrier -> no MFMA-latency wait)
        SOFTMAX_PV(0, Vs[cur]);
        SOFTMAX_PV(1, Vs[cur]);

        // produce sacc(it+1) for next iteration
        QK_TILE(Ks[nxt]);

        __syncthreads();  // drains DMA (vmcnt) + orders buffer reuse
    }
    // tail: consume sacc(31); V(31) staged at it=30 into Vs[1]
    SOFTMAX_PV(0, Vs[1]);
    SOFTMAX_PV(1, Vs[1]);

    // epilogue: full l per q (cross-half add), redistribute 1/l to o's row layout
    float lfull = lacc + __shfl_xor(lacc, 32, 64);
    float rinv = 1.0f / lfull;  // valid for q = wq + l31 (both halves)
    const int b_ = bh >> 4, h = bh & 15;
#pragma unroll
    for (int r = 0; r < 16; ++r) {
        const int qrow = (r & 3) + 8 * (r >> 2) + 4 * hi;
        const float rl = __shfl(rinv, qrow, 64);
        const int s = q0 + wq + qrow;
#pragma unroll
        for (int nt = 0; nt < 2; ++nt) {
            const int d = nt * 32 + l31;
            Oa[(size_t)(b_ * 2048 + s) * 1024 + h * 64 + d] =
                (unsigned short)f2bf(o[nt][r] * rl);
        }
    }
}

extern "C" void kernel_launch(void* const* d_in, const int* in_sizes, int n_in,
                              void* d_out, int out_size, void* d_ws, size_t ws_size,
                              hipStream_t stream) {
    const float* q  = (const float*)d_in[0];
    const float* k  = (const float*)d_in[1];
    const float* v  = (const float*)d_in[2];
    const float* Wq = (const float*)d_in[3];
    const float* bq = (const float*)d_in[4];
    const float* Wk = (const float*)d_in[5];
    const float* bk = (const float*)d_in[6];
    const float* Wv = (const float*)d_in[7];
    const float* bv = (const float*)d_in[8];
    const float* Wo = (const float*)d_in[9];
    const float* bo = (const float*)d_in[10];

    const size_t E = (size_t)8192 * 1024;
    const size_t WE = (size_t)1024 * 1024;
    // aliasing (sequential dependency chain): r0=q_bf->Kh ; r1=k_bf->Vt ; r2=v_bf->Ao ; r3=Qh
    unsigned short* r0 = (unsigned short*)d_ws;
    unsigned short* r1 = r0 + E;
    unsigned short* r2 = r1 + E;
    unsigned short* r3 = r2 + E;
    unsigned short* wqb = r3 + E;
    unsigned short* wkb = wqb + WE;
    unsigned short* wvb = wkb + WE;
    unsigned short* wob = wvb + WE;

    CvtArgs ca;
    ca.s[0] = q; ca.d[0] = r0;
    ca.s[1] = k; ca.d[1] = r1;
    ca.s[2] = v; ca.d[2] = r2;
    ca.s[3] = q; ca.d[3] = r0;  // unused (grid.y = 3)
    ca.n4 = (int)(E / 4);
    cvt_bf16<<<dim3(1024, 3), 256, 0, stream>>>(ca);

    CvtArgs cw;
    cw.s[0] = Wq; cw.d[0] = wqb;
    cw.s[1] = Wk; cw.d[1] = wkb;
    cw.s[2] = Wv; cw.d[2] = wvb;
    cw.s[3] = Wo; cw.d[3] = wob;
    cw.n4 = (int)(WE / 4);
    cvt_bf16<<<dim3(256, 4), 256, 0, stream>>>(cw);

    const float QSCALE = 0.125f * 1.44269504088896340736f;  // fold log2(e) for exp2

    QkvArgs ga;
    ga.A[0] = r0; ga.W[0] = wqb; ga.bias[0] = bq; ga.scale[0] = QSCALE; ga.out[0] = r3; ga.mode[0] = 1;
    ga.A[1] = r1; ga.W[1] = wkb; ga.bias[1] = bk; ga.scale[1] = 1.0f;   ga.out[1] = r0; ga.mode[1] = 1;
    ga.A[2] = r2; ga.W[2] = wvb; ga.bias[2] = bv; ga.scale[2] = 1.0f;   ga.out[2] = r1; ga.mode[2] = 2;
    gemm_qkv<<<dim3(8, 64, 3), 256, 0, stream>>>(ga);

    flash_attn<<<dim3(16, 64), 256, 0, stream>>>(r3, r0, r1, r2);  // Ao = r2
    gemm_wo<<<dim3(8, 64), 256, 0, stream>>>(r2, wob, bo, (float*)d_out);
}

// Round 5
// 358.500 us; speedup vs baseline: 1.0718x; 1.0281x over previous
//
#include <hip/hip_runtime.h>

// MHA: B=4, S=2048, D=1024, H=16, Dh=64.  M = B*S = 8192.
// bf16 MFMA layouts (verified):
//   32x32x16  C/D: col=lane&31, row=(r&3)+8*(r>>2)+4*(lane>>5)
//             A[m=lane&31][k=(lane>>5)*8+j] ; B[k=(lane>>5)*8+j][n=lane&31]
// GEMM v4: rotated double-buffer (R4: 115->99.5us) + XCD-chunked swizzle (T1).
// R4 PMC: FETCH 200MB vs 54MB ideal -> A-panels diluted across 8 XCD L2s.
// Remap: XCD k owns m-panels [8k,8k+8) x all n => L2 set = 2MB A + 2MB W = 4MB.
// Flash v7 (unchanged): rotated pipeline, in-register P via permlane32_swap,
// setprio on MFMA clusters, launch_bounds(256,4).

typedef short bf16x8 __attribute__((ext_vector_type(8)));
typedef short bf16x4 __attribute__((ext_vector_type(4)));
typedef float f32x4 __attribute__((ext_vector_type(4)));
typedef float f32x16 __attribute__((ext_vector_type(16)));
typedef unsigned int u32x4 __attribute__((ext_vector_type(4)));

__device__ __forceinline__ short f2bf(float x) {  // RNE
    union { float f; unsigned int u; } un; un.f = x;
    unsigned int u = un.u;
    return (short)(unsigned short)((u + 0x7fffu + ((u >> 16) & 1u)) >> 16);
}

__device__ __forceinline__ void gll16(const void* g, void* l) {
    __builtin_amdgcn_global_load_lds(
        (const __attribute__((address_space(1))) void*)g,
        (__attribute__((address_space(3))) void*)l, 16, 0, 0);
}

// v_permlane32_swap_b32 a, b :  tmp = a.hi32lanes; a.hi = b.lo; b.lo = tmp
__device__ __forceinline__ void plswap(unsigned& a, unsigned& b) {
    asm("v_permlane32_swap_b32 %0, %1" : "+v"(a), "+v"(b));
}

// ---- fused fp32 -> bf16 convert ----
struct CvtArgs { const float* s[4]; unsigned short* d[4]; int n4; };
__global__ __launch_bounds__(256) void cvt_bf16(CvtArgs ca) {
    const float* s = ca.s[blockIdx.y];
    unsigned short* d = ca.d[blockIdx.y];
    int i = blockIdx.x * blockDim.x + threadIdx.x;
    int stride = gridDim.x * blockDim.x;
    const float4* s4 = reinterpret_cast<const float4*>(s);
    bf16x4* d4 = reinterpret_cast<bf16x4*>(d);
    for (; i < ca.n4; i += stride) {
        float4 x = s4[i];
        bf16x4 y;
        y[0] = f2bf(x.x); y[1] = f2bf(x.y); y[2] = f2bf(x.z); y[3] = f2bf(x.w);
        d4[i] = y;
    }
}

// XCD-chunked remap for an (8 n) x (64 m) tile grid, 512 blocks per z-slice.
// Round-robin dispatch puts or%8 on XCD or%8; give that XCD the contiguous
// logical chunk [64*(or%8), 64*(or%8)+64) so its 8 m-panels + full W fit L2.
__device__ __forceinline__ void xcd_remap(int& m0, int& n0) {
    const int orid = blockIdx.x + 8 * blockIdx.y;
    const int swz = ((orid & 7) << 6) | (orid >> 3);
    n0 = (swz & 7) * 128;
    m0 = (swz >> 3) * 128;
}

// ---- GEMM core: C[8192][1024] = A @ W^T, val = (acc+bias)*scale ----
// mode 0: fp32 [M][N] ; mode 1: bf16 [b*16+h][s][d] ; mode 2: bf16 [b*16+h][d][s]
// Rotated double-buffer: stage K-tile t+1 while computing t; one barrier/iter.
__device__ __forceinline__ void gemm_core(const unsigned short* __restrict__ A,
                                          const unsigned short* __restrict__ W,
                                          const float* __restrict__ bias,
                                          float scale, void* __restrict__ out,
                                          int mode) {
    __shared__ unsigned short As[2][128 * 64];  // 128 rows x 128B, source-swizzled
    __shared__ unsigned short Bs[2][128 * 64];
    const int tid = threadIdx.x;
    int m0, n0;
    xcd_remap(m0, n0);
    const int wave = tid >> 6, lane = tid & 63;
    const int wm = (wave >> 1) * 64, wn = (wave & 1) * 64;
    const int l15 = lane & 15, quad = lane >> 4;
    const int srow = tid >> 3;
    const int scol = ((tid & 7) ^ (srow & 7)) * 8;
    const int cb = (l15 & 7);

    f32x4 acc[4][4] = {};

    // prologue: stage K-tile 0 into buf 0
#pragma unroll
    for (int ro = 0; ro < 4; ++ro) {
        gll16(&A[(size_t)(m0 + ro * 32 + srow) * 1024 + scol], &As[0][ro * 2048 + tid * 8]);
        gll16(&W[(size_t)(n0 + ro * 32 + srow) * 1024 + scol], &Bs[0][ro * 2048 + tid * 8]);
    }
    __syncthreads();  // vmcnt(0) drain + barrier

    for (int kt = 0; kt < 16; ++kt) {
        const int cur = kt & 1;
        if (kt < 15) {  // issue next-tile DMA into the other buffer (no wait)
            const int k0 = (kt + 1) * 64;
#pragma unroll
            for (int ro = 0; ro < 4; ++ro) {
                gll16(&A[(size_t)(m0 + ro * 32 + srow) * 1024 + k0 + scol], &As[cur ^ 1][ro * 2048 + tid * 8]);
                gll16(&W[(size_t)(n0 + ro * 32 + srow) * 1024 + k0 + scol], &Bs[cur ^ 1][ro * 2048 + tid * 8]);
            }
        }
#pragma unroll
        for (int kk = 0; kk < 2; ++kk) {
            const int co = ((4 * kk + quad) ^ cb) * 8;
            bf16x8 a[4], b[4];
#pragma unroll
            for (int i = 0; i < 4; ++i)
                a[i] = *reinterpret_cast<bf16x8*>(&As[cur][(wm + i * 16 + l15) * 64 + co]);
#pragma unroll
            for (int j = 0; j < 4; ++j)
                b[j] = *reinterpret_cast<bf16x8*>(&Bs[cur][(wn + j * 16 + l15) * 64 + co]);
#pragma unroll
            for (int i = 0; i < 4; ++i)
#pragma unroll
                for (int j = 0; j < 4; ++j)
                    acc[i][j] = __builtin_amdgcn_mfma_f32_16x16x32_bf16(a[i], b[j], acc[i][j], 0, 0, 0);
        }
        __syncthreads();  // waves done reading buf[cur]; next-tile DMA landed
    }

#pragma unroll
    for (int i = 0; i < 4; ++i) {
#pragma unroll
        for (int j = 0; j < 4; ++j) {
#pragma unroll
            for (int r = 0; r < 4; ++r) {
                int m = m0 + wm + i * 16 + quad * 4 + r;
                int n = n0 + wn + j * 16 + l15;
                float val = (acc[i][j][r] + bias[n]) * scale;
                if (mode == 0) {
                    reinterpret_cast<float*>(out)[(size_t)m * 1024 + n] = val;
                } else {
                    int b_ = m >> 11, s = m & 2047, h = n >> 6, d = n & 63;
                    size_t off = (mode == 1)
                                     ? ((size_t)((b_ * 16 + h) * 2048 + s) * 64 + d)
                                     : ((size_t)((b_ * 16 + h) * 64 + d) * 2048 + s);
                    reinterpret_cast<unsigned short*>(out)[off] = (unsigned short)f2bf(val);
                }
            }
        }
    }
}

struct QkvArgs {
    const unsigned short* A[3];
    const unsigned short* W[3];
    const float* bias[3];
    float scale[3];
    unsigned short* out[3];
    int mode[3];
};
__global__ __launch_bounds__(256) void gemm_qkv(QkvArgs ga) {
    int z = blockIdx.z;
    gemm_core(ga.A[z], ga.W[z], ga.bias[z], ga.scale[z], ga.out[z], ga.mode[z]);
}

__global__ __launch_bounds__(256) void gemm_wo(const unsigned short* __restrict__ A,
                                               const unsigned short* __restrict__ W,
                                               const float* __restrict__ bias,
                                               float* __restrict__ out) {
    gemm_core(A, W, bias, 1.0f, out, 0);
}

// ---- Flash v7: rotated pipeline, 32x32x16, in-register P ----
// Qh,Kh: [64][2048][64]; Vt: [64][64][2048]; Oa: [8192][1024] bf16.
// Q pre-scaled by 0.125*log2(e) -> exp2 directly. Block = (bh, 128 q), 4 waves.

// exp2(sacc[MT]) -> row-sum into lacc -> pack bf16 -> permlane -> 4 PV MFMAs
#define SOFTMAX_PV(MT, VBASE)                                                        \
    {                                                                                \
        float e[16];                                                                 \
        _Pragma("unroll")                                                            \
        for (int r = 0; r < 16; ++r) e[r] = __builtin_amdgcn_exp2f(sacc[MT][r]);     \
        lacc += ((e[0] + e[1]) + (e[2] + e[3])) + ((e[4] + e[5]) + (e[6] + e[7])) +  \
                ((e[8] + e[9]) + (e[10] + e[11])) + ((e[12] + e[13]) + (e[14] + e[15])); \
        unsigned w[8];                                                               \
        _Pragma("unroll")                                                            \
        for (int t = 0; t < 8; ++t) {                                                \
            union { float f; unsigned u; } a0{e[2 * t]}, a1{e[2 * t + 1]};           \
            w[t] = __builtin_amdgcn_perm(a1.u + 0x8000u, a0.u + 0x8000u, 0x07060302u); \
        }                                                                            \
        plswap(w[0], w[2]); plswap(w[1], w[3]);                                      \
        plswap(w[4], w[6]); plswap(w[5], w[7]);                                      \
        u32x4 t0; t0[0] = w[0]; t0[1] = w[1]; t0[2] = w[2]; t0[3] = w[3];            \
        u32x4 t1; t1[0] = w[4]; t1[1] = w[5]; t1[2] = w[6]; t1[3] = w[7];            \
        bf16x8 pa0 = __builtin_bit_cast(bf16x8, t0);                                 \
        bf16x8 pa1 = __builtin_bit_cast(bf16x8, t1);                                 \
        __builtin_amdgcn_s_setprio(1);                                               \
        _Pragma("unroll")                                                            \
        for (int nt = 0; nt < 2; ++nt) {                                             \
            bf16x8 bv0 = *reinterpret_cast<const bf16x8*>(&(VBASE)[rowoff[nt] + chx[2 * (MT)]]); \
            bf16x8 bv1 = *reinterpret_cast<const bf16x8*>(&(VBASE)[rowoff[nt] + chx[2 * (MT) + 1]]); \
            o[nt] = __builtin_amdgcn_mfma_f32_32x32x16_bf16(pa0, bv0, o[nt], 0, 0, 0); \
            o[nt] = __builtin_amdgcn_mfma_f32_32x32x16_bf16(pa1, bv1, o[nt], 0, 0, 0); \
        }                                                                            \
        __builtin_amdgcn_s_setprio(0);                                               \
    }

// sacc = K_tile . Q^T from KBASE (8 MFMAs, 8 ds_read_b128)
#define QK_TILE(KBASE)                                                               \
    {                                                                                \
        f32x16 zz = {};                                                              \
        sacc[0] = zz; sacc[1] = zz;                                                  \
        __builtin_amdgcn_s_setprio(1);                                               \
        _Pragma("unroll")                                                            \
        for (int c = 0; c < 4; ++c) {                                                \
            bf16x8 ak0 = *reinterpret_cast<const bf16x8*>(&(KBASE)[rowoff[0] + chx[c]]); \
            bf16x8 ak1 = *reinterpret_cast<const bf16x8*>(&(KBASE)[rowoff[1] + chx[c]]); \
            sacc[0] = __builtin_amdgcn_mfma_f32_32x32x16_bf16(ak0, qreg[c], sacc[0], 0, 0, 0); \
            sacc[1] = __builtin_amdgcn_mfma_f32_32x32x16_bf16(ak1, qreg[c], sacc[1], 0, 0, 0); \
        }                                                                            \
        __builtin_amdgcn_s_setprio(0);                                               \
    }

__global__ __launch_bounds__(256, 4) void flash_attn(const unsigned short* __restrict__ Qh,
                                                     const unsigned short* __restrict__ Kh,
                                                     const unsigned short* __restrict__ Vt,
                                                     unsigned short* __restrict__ Oa) {
    __shared__ unsigned short Ks[2][64 * 64];   // [kv][d], source-swizzled chunks
    __shared__ unsigned short Vs[2][64 * 64];   // V^T window [d][kv]
    const int tid = threadIdx.x;
    const int bh = blockIdx.y;
    const int q0 = blockIdx.x * 128;
    const unsigned short* Qb = Qh + (size_t)bh * 2048 * 64;
    const unsigned short* Kb = Kh + (size_t)bh * 2048 * 64;
    const unsigned short* Vb = Vt + (size_t)bh * 64 * 2048;
    const int wave = tid >> 6, lane = tid & 63;
    const int l31 = lane & 31, hi = lane >> 5;
    const int wq = wave * 32;
    const int srow = tid >> 3;                       // 0..31 per round
    const int scol = ((tid & 7) ^ (srow & 7)) * 8;   // swizzled source chunk

    // per-lane LDS read offsets (in shorts): row stride 64, chunk XOR row&7
    int chx[4], rowoff[2];
#pragma unroll
    for (int c = 0; c < 4; ++c) chx[c] = ((c * 2 + hi) ^ (l31 & 7)) * 8;
    rowoff[0] = l31 * 64;
    rowoff[1] = (32 + l31) * 64;

    // Q fragments (B-operand): qreg[c] = Q[q0+wq+l31][c*16 + hi*8 .. +8]
    bf16x8 qreg[4];
#pragma unroll
    for (int c = 0; c < 4; ++c)
        qreg[c] = *reinterpret_cast<const bf16x8*>(
            &Qb[(size_t)(q0 + wq + l31) * 64 + c * 16 + hi * 8]);

    f32x16 o[2] = {};
    f32x16 sacc[2];
    float lacc = 0.f;

    // prologue: stage K(0)->Ks[0], V(0)->Vs[0], K(1)->Ks[1]
#pragma unroll
    for (int ro = 0; ro < 2; ++ro) {
        gll16(&Kb[(size_t)(ro * 32 + srow) * 64 + scol], &Ks[0][ro * 2048 + tid * 8]);
        gll16(&Vb[(size_t)(ro * 32 + srow) * 2048 + scol], &Vs[0][ro * 2048 + tid * 8]);
        gll16(&Kb[(size_t)(64 + ro * 32 + srow) * 64 + scol], &Ks[1][ro * 2048 + tid * 8]);
    }
    __syncthreads();
    QK_TILE(Ks[0]);      // sacc = S(0)
    __syncthreads();     // all waves done with Ks[0] before iter-0 DMA overwrites it

    for (int it = 0; it < 31; ++it) {
        const int cur = it & 1, nxt = cur ^ 1;
        // prefetch: K(it+2) into the K buffer freed by last iter's QK
        if (it < 30) {
            const int kvn = (it + 2) * 64;
#pragma unroll
            for (int ro = 0; ro < 2; ++ro)
                gll16(&Kb[(size_t)(kvn + ro * 32 + srow) * 64 + scol], &Ks[cur][ro * 2048 + tid * 8]);
        }
        // prefetch: V(it+1) into the V buffer freed by last iter's PV
        {
            const int kvn = (it + 1) * 64;
#pragma unroll
            for (int ro = 0; ro < 2; ++ro)
                gll16(&Vb[(size_t)(ro * 32 + srow) * 2048 + kvn + scol], &Vs[nxt][ro * 2048 + tid * 8]);
        }

        // consume sacc(it) (produced before last barrier -> no MFMA-latency wait)
        SOFTMAX_PV(0, Vs[cur]);
        SOFTMAX_PV(1, Vs[cur]);

        // produce sacc(it+1) for next iteration
        QK_TILE(Ks[nxt]);

        __syncthreads();  // drains DMA (vmcnt) + orders buffer reuse
    }
    // tail: consume sacc(31); V(31) staged at it=30 into Vs[1]
    SOFTMAX_PV(0, Vs[1]);
    SOFTMAX_PV(1, Vs[1]);

    // epilogue: full l per q (cross-half add), redistribute 1/l to o's row layout
    float lfull = lacc + __shfl_xor(lacc, 32, 64);
    float rinv = 1.0f / lfull;  // valid for q = wq + l31 (both halves)
    const int b_ = bh >> 4, h = bh & 15;
#pragma unroll
    for (int r = 0; r < 16; ++r) {
        const int qrow = (r & 3) + 8 * (r >> 2) + 4 * hi;
        const float rl = __shfl(rinv, qrow, 64);
        const int s = q0 + wq + qrow;
#pragma unroll
        for (int nt = 0; nt < 2; ++nt) {
            const int d = nt * 32 + l31;
            Oa[(size_t)(b_ * 2048 + s) * 1024 + h * 64 + d] =
                (unsigned short)f2bf(o[nt][r] * rl);
        }
    }
}

extern "C" void kernel_launch(void* const* d_in, const int* in_sizes, int n_in,
                              void* d_out, int out_size, void* d_ws, size_t ws_size,
                              hipStream_t stream) {
    const float* q  = (const float*)d_in[0];
    const float* k  = (const float*)d_in[1];
    const float* v  = (const float*)d_in[2];
    const float* Wq = (const float*)d_in[3];
    const float* bq = (const float*)d_in[4];
    const float* Wk = (const float*)d_in[5];
    const float* bk = (const float*)d_in[6];
    const float* Wv = (const float*)d_in[7];
    const float* bv = (const float*)d_in[8];
    const float* Wo = (const float*)d_in[9];
    const float* bo = (const float*)d_in[10];

    const size_t E = (size_t)8192 * 1024;
    const size_t WE = (size_t)1024 * 1024;
    // aliasing (sequential dependency chain): r0=q_bf->Kh ; r1=k_bf->Vt ; r2=v_bf->Ao ; r3=Qh
    unsigned short* r0 = (unsigned short*)d_ws;
    unsigned short* r1 = r0 + E;
    unsigned short* r2 = r1 + E;
    unsigned short* r3 = r2 + E;
    unsigned short* wqb = r3 + E;
    unsigned short* wkb = wqb + WE;
    unsigned short* wvb = wkb + WE;
    unsigned short* wob = wvb + WE;

    CvtArgs ca;
    ca.s[0] = q; ca.d[0] = r0;
    ca.s[1] = k; ca.d[1] = r1;
    ca.s[2] = v; ca.d[2] = r2;
    ca.s[3] = q; ca.d[3] = r0;  // unused (grid.y = 3)
    ca.n4 = (int)(E / 4);
    cvt_bf16<<<dim3(1024, 3), 256, 0, stream>>>(ca);

    CvtArgs cw;
    cw.s[0] = Wq; cw.d[0] = wqb;
    cw.s[1] = Wk; cw.d[1] = wkb;
    cw.s[2] = Wv; cw.d[2] = wvb;
    cw.s[3] = Wo; cw.d[3] = wob;
    cw.n4 = (int)(WE / 4);
    cvt_bf16<<<dim3(256, 4), 256, 0, stream>>>(cw);

    const float QSCALE = 0.125f * 1.44269504088896340736f;  // fold log2(e) for exp2

    QkvArgs ga;
    ga.A[0] = r0; ga.W[0] = wqb; ga.bias[0] = bq; ga.scale[0] = QSCALE; ga.out[0] = r3; ga.mode[0] = 1;
    ga.A[1] = r1; ga.W[1] = wkb; ga.bias[1] = bk; ga.scale[1] = 1.0f;   ga.out[1] = r0; ga.mode[1] = 1;
    ga.A[2] = r2; ga.W[2] = wvb; ga.bias[2] = bv; ga.scale[2] = 1.0f;   ga.out[2] = r1; ga.mode[2] = 2;
    gemm_qkv<<<dim3(8, 64, 3), 256, 0, stream>>>(ga);

    flash_attn<<<dim3(16, 64), 256, 0, stream>>>(r3, r0, r1, r2);  // Ao = r2
    gemm_wo<<<dim3(8, 64), 256, 0, stream>>>(r2, wob, bo, (float*)d_out);
}

// Round 6
// 349.699 us; speedup vs baseline: 1.0988x; 1.0252x over previous
//
#include <hip/hip_runtime.h>

// MHA: B=4, S=2048, D=1024, H=16, Dh=64.  M = B*S = 8192.
// GEMM v5 (8-phase class, T3+T4): BM=128 BN=256 BK=64, 512 thr (8 waves 2Mx4N),
// 3-slot LDS ring (A 48KB + B 96KB = 144KB), prefetch distance 2 K-tiles,
// counted s_waitcnt vmcnt(6) at tile boundaries (NEVER 0 in-loop), raw
// s_barrier (no __syncthreads -> no forced vmcnt(0) drain), per-phase
// {8 ds_read_b128 || 3 gll16 -> bar -> setprio 16 MFMA -> bar}.
// Wait-safety (derived): tile kt staged during kt-2 (6 loads/thread); at each
// boundary vmcnt(6) leaves only kt+2's loads in flight; own-wait+barrier
// validates cross-wave. Slot (kt+2)%3 freed by kt-1's reads >=2 barriers ago.
// Grid 4x64 = 256 blocks/z -> exact 1-block/CU rounds. XCD chunk swizzle kept
// (R5: FETCH 200->49MB).
// Flash v7 (unchanged): rotated pipeline, in-register P via permlane32_swap,
// setprio on MFMA clusters, launch_bounds(256,4).

typedef short bf16x8 __attribute__((ext_vector_type(8)));
typedef short bf16x4 __attribute__((ext_vector_type(4)));
typedef float f32x4 __attribute__((ext_vector_type(4)));
typedef float f32x16 __attribute__((ext_vector_type(16)));
typedef unsigned int u32x4 __attribute__((ext_vector_type(4)));

__device__ __forceinline__ short f2bf(float x) {  // RNE
    union { float f; unsigned int u; } un; un.f = x;
    unsigned int u = un.u;
    return (short)(unsigned short)((u + 0x7fffu + ((u >> 16) & 1u)) >> 16);
}

__device__ __forceinline__ void gll16(const void* g, void* l) {
    __builtin_amdgcn_global_load_lds(
        (const __attribute__((address_space(1))) void*)g,
        (__attribute__((address_space(3))) void*)l, 16, 0, 0);
}

// v_permlane32_swap_b32 a, b :  tmp = a.hi32lanes; a.hi = b.lo; b.lo = tmp
__device__ __forceinline__ void plswap(unsigned& a, unsigned& b) {
    asm("v_permlane32_swap_b32 %0, %1" : "+v"(a), "+v"(b));
}

#define SBAR()   asm volatile("s_barrier" ::: "memory")
#define VMCNT6() asm volatile("s_waitcnt vmcnt(6)" ::: "memory")

// ---- fused fp32 -> bf16 convert ----
struct CvtArgs { const float* s[4]; unsigned short* d[4]; int n4; };
__global__ __launch_bounds__(256) void cvt_bf16(CvtArgs ca) {
    const float* s = ca.s[blockIdx.y];
    unsigned short* d = ca.d[blockIdx.y];
    int i = blockIdx.x * blockDim.x + threadIdx.x;
    int stride = gridDim.x * blockDim.x;
    const float4* s4 = reinterpret_cast<const float4*>(s);
    bf16x4* d4 = reinterpret_cast<bf16x4*>(d);
    for (; i < ca.n4; i += stride) {
        float4 x = s4[i];
        bf16x4 y;
        y[0] = f2bf(x.x); y[1] = f2bf(x.y); y[2] = f2bf(x.z); y[3] = f2bf(x.w);
        d4[i] = y;
    }
}

// ---- GEMM core v5: C[8192][1024] = A @ W^T, val = (acc+bias)*scale ----
// mode 0: fp32 [M][N] ; mode 1: bf16 [b*16+h][s][d] ; mode 2: bf16 [b*16+h][d][s]
__device__ __forceinline__ void gemm_core(const unsigned short* __restrict__ A,
                                          const unsigned short* __restrict__ W,
                                          const float* __restrict__ bias,
                                          float scale, void* __restrict__ out,
                                          int mode) {
    __shared__ unsigned short As[3 * 128 * 64];  // 3-slot ring, src-swizzled
    __shared__ unsigned short Bs[3 * 256 * 64];
    const int tid = threadIdx.x;
    // XCD chunk remap: 256 blocks/z, XCD k owns m-panels [8k,8k+8) x all 4 n
    const int orid = blockIdx.x + 4 * blockIdx.y;
    const int swz = ((orid & 7) << 5) | (orid >> 3);
    const int n0 = (swz & 3) * 256;
    const int m0 = (swz >> 2) * 128;
    const int wave = tid >> 6, lane = tid & 63;
    const int wmr = (wave >> 2) * 64, wnr = (wave & 3) * 64;
    const int l15 = lane & 15, quad = lane >> 4;
    const int cb = l15 & 7;
    const int srow = tid >> 3;                      // 0..63
    const int scol = ((tid & 7) ^ (srow & 7)) * 8;  // swizzled source chunk

    f32x4 acc[4][4] = {};

#define SA(kt, sl)                                                                  \
    {                                                                               \
        gll16(&A[(size_t)(m0 + srow) * 1024 + (kt) * 64 + scol],                    \
              &As[(sl) * 8192 + tid * 8]);                                          \
        gll16(&A[(size_t)(m0 + 64 + srow) * 1024 + (kt) * 64 + scol],               \
              &As[(sl) * 8192 + 4096 + tid * 8]);                                   \
    }
#define SB(kt, sl, ro)                                                              \
    gll16(&W[(size_t)(n0 + (ro) * 64 + srow) * 1024 + (kt) * 64 + scol],            \
          &Bs[(sl) * 16384 + (ro) * 4096 + tid * 8]);

    // prologue: tiles 0 (slot 0) and 1 (slot 1): 6 loads each, in order
    SA(0, 0); SB(0, 0, 0); SB(0, 0, 1); SB(0, 0, 2); SB(0, 0, 3);
    SA(1, 1); SB(1, 1, 0); SB(1, 1, 1); SB(1, 1, 2); SB(1, 1, 3);
    VMCNT6();  // tile 0's 6 loads landed (tile 1's may be in flight)
    __builtin_amdgcn_sched_barrier(0);
    SBAR();
    __builtin_amdgcn_sched_barrier(0);

    int sl = 0;  // read slot (= kt % 3)
    for (int kt = 0; kt < 16; ++kt) {
        const int ss = (sl + 2 >= 3) ? sl - 1 : sl + 2;  // (kt+2) % 3
        const unsigned short* Ab = &As[sl * 8192];
        const unsigned short* Bb = &Bs[sl * 16384];
        // ---- phase 0 (kk = 0) ----
        {
            const int co = (quad ^ cb) * 8;
            bf16x8 a[4], b[4];
#pragma unroll
            for (int i = 0; i < 4; ++i)
                a[i] = *reinterpret_cast<const bf16x8*>(&Ab[(wmr + i * 16 + l15) * 64 + co]);
#pragma unroll
            for (int j = 0; j < 4; ++j)
                b[j] = *reinterpret_cast<const bf16x8*>(&Bb[(wnr + j * 16 + l15) * 64 + co]);
            if (kt < 14) { SA(kt + 2, ss); SB(kt + 2, ss, 0); }
            SBAR();
            __builtin_amdgcn_sched_barrier(0);
            __builtin_amdgcn_s_setprio(1);
#pragma unroll
            for (int i = 0; i < 4; ++i)
#pragma unroll
                for (int j = 0; j < 4; ++j)
                    acc[i][j] = __builtin_amdgcn_mfma_f32_16x16x32_bf16(a[i], b[j], acc[i][j], 0, 0, 0);
            __builtin_amdgcn_s_setprio(0);
            SBAR();
            __builtin_amdgcn_sched_barrier(0);
        }
        // ---- phase 1 (kk = 1) ----
        {
            const int co = ((4 + quad) ^ cb) * 8;
            bf16x8 a[4], b[4];
#pragma unroll
            for (int i = 0; i < 4; ++i)
                a[i] = *reinterpret_cast<const bf16x8*>(&Ab[(wmr + i * 16 + l15) * 64 + co]);
#pragma unroll
            for (int j = 0; j < 4; ++j)
                b[j] = *reinterpret_cast<const bf16x8*>(&Bb[(wnr + j * 16 + l15) * 64 + co]);
            if (kt < 14) { SB(kt + 2, ss, 1); SB(kt + 2, ss, 2); SB(kt + 2, ss, 3); }
            if (kt < 15) {
                VMCNT6();  // next tile's 6 loads landed; only kt+2's in flight
                __builtin_amdgcn_sched_barrier(0);
            }
            SBAR();
            __builtin_amdgcn_sched_barrier(0);
            __builtin_amdgcn_s_setprio(1);
#pragma unroll
            for (int i = 0; i < 4; ++i)
#pragma unroll
                for (int j = 0; j < 4; ++j)
                    acc[i][j] = __builtin_amdgcn_mfma_f32_16x16x32_bf16(a[i], b[j], acc[i][j], 0, 0, 0);
            __builtin_amdgcn_s_setprio(0);
            SBAR();
            __builtin_amdgcn_sched_barrier(0);
        }
        sl = (sl + 1 == 3) ? 0 : sl + 1;
    }
#undef SA
#undef SB

#pragma unroll
    for (int i = 0; i < 4; ++i) {
#pragma unroll
        for (int j = 0; j < 4; ++j) {
#pragma unroll
            for (int r = 0; r < 4; ++r) {
                int m = m0 + wmr + i * 16 + quad * 4 + r;
                int n = n0 + wnr + j * 16 + l15;
                float val = (acc[i][j][r] + bias[n]) * scale;
                if (mode == 0) {
                    reinterpret_cast<float*>(out)[(size_t)m * 1024 + n] = val;
                } else {
                    int b_ = m >> 11, s = m & 2047, h = n >> 6, d = n & 63;
                    size_t off = (mode == 1)
                                     ? ((size_t)((b_ * 16 + h) * 2048 + s) * 64 + d)
                                     : ((size_t)((b_ * 16 + h) * 64 + d) * 2048 + s);
                    reinterpret_cast<unsigned short*>(out)[off] = (unsigned short)f2bf(val);
                }
            }
        }
    }
}

struct QkvArgs {
    const unsigned short* A[3];
    const unsigned short* W[3];
    const float* bias[3];
    float scale[3];
    unsigned short* out[3];
    int mode[3];
};
__global__ __launch_bounds__(512, 2) void gemm_qkv(QkvArgs ga) {
    int z = blockIdx.z;
    gemm_core(ga.A[z], ga.W[z], ga.bias[z], ga.scale[z], ga.out[z], ga.mode[z]);
}

__global__ __launch_bounds__(512, 2) void gemm_wo(const unsigned short* __restrict__ A,
                                                  const unsigned short* __restrict__ W,
                                                  const float* __restrict__ bias,
                                                  float* __restrict__ out) {
    gemm_core(A, W, bias, 1.0f, out, 0);
}

// ---- Flash v7: rotated pipeline, 32x32x16, in-register P ----
// Qh,Kh: [64][2048][64]; Vt: [64][64][2048]; Oa: [8192][1024] bf16.
// Q pre-scaled by 0.125*log2(e) -> exp2 directly. Block = (bh, 128 q), 4 waves.

// exp2(sacc[MT]) -> row-sum into lacc -> pack bf16 pairs -> permlane -> 4 PV MFMAs
#define SOFTMAX_PV(MT, VBASE)                                                        \
    {                                                                                \
        float e[16];                                                                 \
        _Pragma("unroll")                                                            \
        for (int r = 0; r < 16; ++r) e[r] = __builtin_amdgcn_exp2f(sacc[MT][r]);     \
        lacc += ((e[0] + e[1]) + (e[2] + e[3])) + ((e[4] + e[5]) + (e[6] + e[7])) +  \
                ((e[8] + e[9]) + (e[10] + e[11])) + ((e[12] + e[13]) + (e[14] + e[15])); \
        unsigned w[8];                                                               \
        _Pragma("unroll")                                                            \
        for (int t = 0; t < 8; ++t) {                                                \
            union { float f; unsigned u; } a0{e[2 * t]}, a1{e[2 * t + 1]};           \
            w[t] = __builtin_amdgcn_perm(a1.u + 0x8000u, a0.u + 0x8000u, 0x07060302u); \
        }                                                                            \
        plswap(w[0], w[2]); plswap(w[1], w[3]);                                      \
        plswap(w[4], w[6]); plswap(w[5], w[7]);                                      \
        u32x4 t0; t0[0] = w[0]; t0[1] = w[1]; t0[2] = w[2]; t0[3] = w[3];            \
        u32x4 t1; t1[0] = w[4]; t1[1] = w[5]; t1[2] = w[6]; t1[3] = w[7];            \
        bf16x8 pa0 = __builtin_bit_cast(bf16x8, t0);                                 \
        bf16x8 pa1 = __builtin_bit_cast(bf16x8, t1);                                 \
        __builtin_amdgcn_s_setprio(1);                                               \
        _Pragma("unroll")                                                            \
        for (int nt = 0; nt < 2; ++nt) {                                             \
            bf16x8 bv0 = *reinterpret_cast<const bf16x8*>(&(VBASE)[rowoff[nt] + chx[2 * (MT)]]); \
            bf16x8 bv1 = *reinterpret_cast<const bf16x8*>(&(VBASE)[rowoff[nt] + chx[2 * (MT) + 1]]); \
            o[nt] = __builtin_amdgcn_mfma_f32_32x32x16_bf16(pa0, bv0, o[nt], 0, 0, 0); \
            o[nt] = __builtin_amdgcn_mfma_f32_32x32x16_bf16(pa1, bv1, o[nt], 0, 0, 0); \
        }                                                                            \
        __builtin_amdgcn_s_setprio(0);                                               \
    }

// sacc = K_tile . Q^T from KBASE (8 MFMAs, 8 ds_read_b128)
#define QK_TILE(KBASE)                                                               \
    {                                                                                \
        f32x16 zz = {};                                                              \
        sacc[0] = zz; sacc[1] = zz;                                                  \
        __builtin_amdgcn_s_setprio(1);                                               \
        _Pragma("unroll")                                                            \
        for (int c = 0; c < 4; ++c) {                                                \
            bf16x8 ak0 = *reinterpret_cast<const bf16x8*>(&(KBASE)[rowoff[0] + chx[c]]); \
            bf16x8 ak1 = *reinterpret_cast<const bf16x8*>(&(KBASE)[rowoff[1] + chx[c]]); \
            sacc[0] = __builtin_amdgcn_mfma_f32_32x32x16_bf16(ak0, qreg[c], sacc[0], 0, 0, 0); \
            sacc[1] = __builtin_amdgcn_mfma_f32_32x32x16_bf16(ak1, qreg[c], sacc[1], 0, 0, 0); \
        }                                                                            \
        __builtin_amdgcn_s_setprio(0);                                               \
    }

__global__ __launch_bounds__(256, 4) void flash_attn(const unsigned short* __restrict__ Qh,
                                                     const unsigned short* __restrict__ Kh,
                                                     const unsigned short* __restrict__ Vt,
                                                     unsigned short* __restrict__ Oa) {
    __shared__ unsigned short Ks[2][64 * 64];   // [kv][d], source-swizzled chunks
    __shared__ unsigned short Vs[2][64 * 64];   // V^T window [d][kv]
    const int tid = threadIdx.x;
    const int bh = blockIdx.y;
    const int q0 = blockIdx.x * 128;
    const unsigned short* Qb = Qh + (size_t)bh * 2048 * 64;
    const unsigned short* Kb = Kh + (size_t)bh * 2048 * 64;
    const unsigned short* Vb = Vt + (size_t)bh * 64 * 2048;
    const int wave = tid >> 6, lane = tid & 63;
    const int l31 = lane & 31, hi = lane >> 5;
    const int wq = wave * 32;
    const int srow = tid >> 3;                       // 0..31 per round
    const int scol = ((tid & 7) ^ (srow & 7)) * 8;   // swizzled source chunk

    // per-lane LDS read offsets (in shorts): row stride 64, chunk XOR row&7
    int chx[4], rowoff[2];
#pragma unroll
    for (int c = 0; c < 4; ++c) chx[c] = ((c * 2 + hi) ^ (l31 & 7)) * 8;
    rowoff[0] = l31 * 64;
    rowoff[1] = (32 + l31) * 64;

    // Q fragments (B-operand): qreg[c] = Q[q0+wq+l31][c*16 + hi*8 .. +8]
    bf16x8 qreg[4];
#pragma unroll
    for (int c = 0; c < 4; ++c)
        qreg[c] = *reinterpret_cast<const bf16x8*>(
            &Qb[(size_t)(q0 + wq + l31) * 64 + c * 16 + hi * 8]);

    f32x16 o[2] = {};
    f32x16 sacc[2];
    float lacc = 0.f;

    // prologue: stage K(0)->Ks[0], V(0)->Vs[0], K(1)->Ks[1]
#pragma unroll
    for (int ro = 0; ro < 2; ++ro) {
        gll16(&Kb[(size_t)(ro * 32 + srow) * 64 + scol], &Ks[0][ro * 2048 + tid * 8]);
        gll16(&Vb[(size_t)(ro * 32 + srow) * 2048 + scol], &Vs[0][ro * 2048 + tid * 8]);
        gll16(&Kb[(size_t)(64 + ro * 32 + srow) * 64 + scol], &Ks[1][ro * 2048 + tid * 8]);
    }
    __syncthreads();
    QK_TILE(Ks[0]);      // sacc = S(0)
    __syncthreads();     // all waves done with Ks[0] before iter-0 DMA overwrites it

    for (int it = 0; it < 31; ++it) {
        const int cur = it & 1, nxt = cur ^ 1;
        // prefetch: K(it+2) into the K buffer freed by last iter's QK
        if (it < 30) {
            const int kvn = (it + 2) * 64;
#pragma unroll
            for (int ro = 0; ro < 2; ++ro)
                gll16(&Kb[(size_t)(kvn + ro * 32 + srow) * 64 + scol], &Ks[cur][ro * 2048 + tid * 8]);
        }
        // prefetch: V(it+1) into the V buffer freed by last iter's PV
        {
            const int kvn = (it + 1) * 64;
#pragma unroll
            for (int ro = 0; ro < 2; ++ro)
                gll16(&Vb[(size_t)(ro * 32 + srow) * 2048 + kvn + scol], &Vs[nxt][ro * 2048 + tid * 8]);
        }

        // consume sacc(it) (produced before last barrier -> no MFMA-latency wait)
        SOFTMAX_PV(0, Vs[cur]);
        SOFTMAX_PV(1, Vs[cur]);

        // produce sacc(it+1) for next iteration
        QK_TILE(Ks[nxt]);

        __syncthreads();  // drains DMA (vmcnt) + orders buffer reuse
    }
    // tail: consume sacc(31); V(31) staged at it=30 into Vs[1]
    SOFTMAX_PV(0, Vs[1]);
    SOFTMAX_PV(1, Vs[1]);

    // epilogue: full l per q (cross-half add), redistribute 1/l to o's row layout
    float lfull = lacc + __shfl_xor(lacc, 32, 64);
    float rinv = 1.0f / lfull;  // valid for q = wq + l31 (both halves)
    const int b_ = bh >> 4, h = bh & 15;
#pragma unroll
    for (int r = 0; r < 16; ++r) {
        const int qrow = (r & 3) + 8 * (r >> 2) + 4 * hi;
        const float rl = __shfl(rinv, qrow, 64);
        const int s = q0 + wq + qrow;
#pragma unroll
        for (int nt = 0; nt < 2; ++nt) {
            const int d = nt * 32 + l31;
            Oa[(size_t)(b_ * 2048 + s) * 1024 + h * 64 + d] =
                (unsigned short)f2bf(o[nt][r] * rl);
        }
    }
}

extern "C" void kernel_launch(void* const* d_in, const int* in_sizes, int n_in,
                              void* d_out, int out_size, void* d_ws, size_t ws_size,
                              hipStream_t stream) {
    const float* q  = (const float*)d_in[0];
    const float* k  = (const float*)d_in[1];
    const float* v  = (const float*)d_in[2];
    const float* Wq = (const float*)d_in[3];
    const float* bq = (const float*)d_in[4];
    const float* Wk = (const float*)d_in[5];
    const float* bk = (const float*)d_in[6];
    const float* Wv = (const float*)d_in[7];
    const float* bv = (const float*)d_in[8];
    const float* Wo = (const float*)d_in[9];
    const float* bo = (const float*)d_in[10];

    const size_t E = (size_t)8192 * 1024;
    const size_t WE = (size_t)1024 * 1024;
    // aliasing (sequential dependency chain): r0=q_bf->Kh ; r1=k_bf->Vt ; r2=v_bf->Ao ; r3=Qh
    unsigned short* r0 = (unsigned short*)d_ws;
    unsigned short* r1 = r0 + E;
    unsigned short* r2 = r1 + E;
    unsigned short* r3 = r2 + E;
    unsigned short* wqb = r3 + E;
    unsigned short* wkb = wqb + WE;
    unsigned short* wvb = wkb + WE;
    unsigned short* wob = wvb + WE;

    CvtArgs ca;
    ca.s[0] = q; ca.d[0] = r0;
    ca.s[1] = k; ca.d[1] = r1;
    ca.s[2] = v; ca.d[2] = r2;
    ca.s[3] = q; ca.d[3] = r0;  // unused (grid.y = 3)
    ca.n4 = (int)(E / 4);
    cvt_bf16<<<dim3(1024, 3), 256, 0, stream>>>(ca);

    CvtArgs cw;
    cw.s[0] = Wq; cw.d[0] = wqb;
    cw.s[1] = Wk; cw.d[1] = wkb;
    cw.s[2] = Wv; cw.d[2] = wvb;
    cw.s[3] = Wo; cw.d[3] = wob;
    cw.n4 = (int)(WE / 4);
    cvt_bf16<<<dim3(256, 4), 256, 0, stream>>>(cw);

    const float QSCALE = 0.125f * 1.44269504088896340736f;  // fold log2(e) for exp2

    QkvArgs ga;
    ga.A[0] = r0; ga.W[0] = wqb; ga.bias[0] = bq; ga.scale[0] = QSCALE; ga.out[0] = r3; ga.mode[0] = 1;
    ga.A[1] = r1; ga.W[1] = wkb; ga.bias[1] = bk; ga.scale[1] = 1.0f;   ga.out[1] = r0; ga.mode[1] = 1;
    ga.A[2] = r2; ga.W[2] = wvb; ga.bias[2] = bv; ga.scale[2] = 1.0f;   ga.out[2] = r1; ga.mode[2] = 2;
    gemm_qkv<<<dim3(4, 64, 3), 512, 0, stream>>>(ga);

    flash_attn<<<dim3(16, 64), 256, 0, stream>>>(r3, r0, r1, r2);  // Ao = r2
    gemm_wo<<<dim3(4, 64), 512, 0, stream>>>(r2, wob, bo, (float*)d_out);
}